// Round 14
// baseline (3016.707 us; speedup 1.0000x reference)
//
#include <hip/hip_runtime.h>
#include <hip/hip_bf16.h>

// ---------------------------------------------------------------------------
// GCNRegression: 4x (GEMM 128x128 + symmetric-norm aggregation + ReLU),
// then global mean pool (128 graphs) + FC(128->1).
//
// R13 notes: lo/hi agg split was NEUTRAL (sector count invariant; ~4.5
// cyc/sector request-rate wall) -> reverted to single-pass agg (R11).
// csr_fill was 73us from 8x edge re-read + RFO -> bucketed build:
// phase A reads edges once, counts deg, partitions packed (src|dst) into
// 8 dst-range buckets (wave-aggregated atomics); per-XCD fill reads only
// its own bucket.
// ---------------------------------------------------------------------------

#define CAPB 216384   // bucket capacity: E/8 + 16K slack (39 sigma)

// ---- phase A: count deg + partition edges into 8 dst-range buckets --------
__global__ __launch_bounds__(256) void bucket_count_kernel(const int* __restrict__ src,
                                                           const int* __restrict__ dst,
                                                           int* __restrict__ deg,
                                                           unsigned int* __restrict__ buckets,
                                                           int* __restrict__ bcount,
                                                           int E, int N) {
    int e = blockIdx.x * blockDim.x + threadIdx.x;
    bool act = (e < E);
    int s = 0, d = 0;
    if (act) { s = src[e]; d = dst[e]; atomicAdd(&deg[d], 1); }

    int R = (N + 7) >> 3;
    int b = 0;                      // b = d / R via compare chain (d < 8R)
    if (d >= (R << 2))   b = 4;
    if (d >= R * (b + 2)) b += 2;
    if (d >= R * (b + 1)) b += 1;
    unsigned pack = ((unsigned)s << 16) | (unsigned)d;

    int lane = threadIdx.x & 63;
    #pragma unroll 1
    for (int bb = 0; bb < 8; bb++) {
        unsigned long long m = __ballot(act && (b == bb));
        if (m == 0ull) continue;
        int leader = __ffsll((long long)m) - 1;
        int cnt = __popcll(m);
        int base = 0;
        if (lane == leader) base = atomicAdd(&bcount[bb], cnt);
        base = __shfl(base, leader);
        if (act && (b == bb)) {
            int off = __popcll(m & ((1ull << lane) - 1ull));
            int pos = base + off;
            if (pos < CAPB)
                buckets[(size_t)bb * CAPB + pos] = pack;
        }
    }
}

// ---- dinv = 1/sqrt(deg+1); zero the pad rows of h0/h1 (4 slices x 32ch) ---
__global__ void dinv_kernel(const int* __restrict__ deg, float* __restrict__ dinv,
                            float* __restrict__ h0, float* __restrict__ h1,
                            int n, int ns) {
    int i = blockIdx.x * blockDim.x + threadIdx.x;
    if (i < n) dinv[i] = (float)(1.0 / sqrt((double)(deg[i] + 1)));
    if (i < 128) {                       // 4 slices x 32 channels pad row
        int p = i >> 5, c = i & 31;
        size_t off = (size_t)p * ns * 32 + (size_t)n * 32 + c;
        h0[off] = 0.f;
        h1[off] = 0.f;
    }
}

// ---- multi-block exclusive scan (3 phases) --------------------------------
__global__ void scan_blocksum_kernel(const int* __restrict__ cnt, int* __restrict__ bsum,
                                     int n2) {
    __shared__ int red[256];
    int t = threadIdx.x;
    int i = blockIdx.x * 256 + t;
    red[t] = (i < n2) ? cnt[i] : 0;
    __syncthreads();
    for (int off = 128; off > 0; off >>= 1) {
        if (t < off) red[t] += red[t + off];
        __syncthreads();
    }
    if (t == 0) bsum[blockIdx.x] = red[0];
}

__global__ __launch_bounds__(1024) void scan_bsum_kernel(const int* __restrict__ bsum,
                                                         int* __restrict__ boff, int nb) {
    __shared__ int s[1024];
    int t = threadIdx.x;
    int v = (t < nb) ? bsum[t] : 0;
    s[t] = v;
    __syncthreads();
    for (int off = 1; off < 1024; off <<= 1) {
        int u = (t >= off) ? s[t - off] : 0;
        __syncthreads();
        s[t] += u;
        __syncthreads();
    }
    if (t < nb) boff[t] = s[t] - v;
}

__global__ void scan_final_kernel(const int* __restrict__ cnt, const int* __restrict__ boff,
                                  int* __restrict__ row, int n2) {
    __shared__ int s[256];
    int t = threadIdx.x;
    int b = blockIdx.x;
    int i = b * 256 + t;
    int v = (i < n2) ? cnt[i] : 0;
    s[t] = v;
    __syncthreads();
    for (int off = 1; off < 256; off <<= 1) {
        int u = (t >= off) ? s[t - off] : 0;
        __syncthreads();
        s[t] += u;
        __syncthreads();
    }
    int incl = s[t];
    int base = boff[b];
    if (i < n2) row[i] = base + incl - v;
    if (i == n2 - 1) row[n2] = base + incl;
}

// ---- CSR fill from per-XCD bucket -----------------------------------------
__global__ __launch_bounds__(256) void csr_fill_kernel(const unsigned int* __restrict__ buckets,
                                                       const int* __restrict__ bcount,
                                                       const int* __restrict__ row,
                                                       int* __restrict__ fill,
                                                       unsigned short* __restrict__ csr) {
    int g  = blockIdx.x & 7;
    int gb = blockIdx.x >> 3;
    int gB = gridDim.x >> 3;
    int cnt = bcount[g];
    const unsigned int* bk = buckets + (size_t)g * CAPB;
    for (int idx = gb * 256 + threadIdx.x; idx < cnt; idx += gB * 256) {
        unsigned pk = bk[idx];
        int d = (int)(pk & 0xffffu);
        int s = (int)(pk >> 16);
        int pos = row[d] + atomicAdd(&fill[d], 1);
        csr[pos] = (unsigned short)s;
    }
}

// ---- GEMM: C = (A @ W) * dinv[row], C channel-blocked [4][ns][32] ---------
__global__ __launch_bounds__(256) void gemm_kernel(const float* __restrict__ A,
                                                   const float* __restrict__ W,
                                                   const float* __restrict__ dinv,
                                                   float* __restrict__ C, int n, int ns,
                                                   int a_blocked) {
    __shared__ float sW[128 * 32];
    int t = threadIdx.x;
    int col0 = (blockIdx.x & 3) * 32;
    int row0 = (blockIdx.x >> 2) * 64;

    #pragma unroll
    for (int i = 0; i < 4; i++) {
        int fidx = t + 256 * i;            // 1024 float4
        int k  = fidx >> 3;
        int c4 = fidx & 7;
        *(float4*)(sW + k * 32 + c4 * 4) =
            *(const float4*)(W + (size_t)k * 128 + col0 + c4 * 4);
    }
    __syncthreads();

    int cg = (t & 7) * 4;
    int rg = (t >> 3) * 2;
    int rbase = row0 + rg;

    int rr_[2];
    #pragma unroll
    for (int r = 0; r < 2; r++) {
        int rr = rbase + r; if (rr > n - 1) rr = n - 1;
        rr_[r] = rr;
    }
    auto aptr = [&](int r, int kb) -> const float* {
        return a_blocked
            ? (A + ((size_t)(kb >> 1) * ns + rr_[r]) * 32 + ((kb & 1) * 16))
            : (A + (size_t)rr_[r] * 128 + kb * 16);
    };

    float acc[2][4];
    #pragma unroll
    for (int r = 0; r < 2; r++)
        #pragma unroll
        for (int c = 0; c < 4; c++) acc[r][c] = 0.f;

    float4 bufA[2][2], bufB[2][2];
    #pragma unroll
    for (int r = 0; r < 2; r++) {
        const float* ap = aptr(r, 0);
        bufA[r][0] = *(const float4*)(ap + 0);
        bufA[r][1] = *(const float4*)(ap + 4);
        bufB[r][0] = *(const float4*)(ap + 8);
        bufB[r][1] = *(const float4*)(ap + 12);
    }

    #pragma unroll 1
    for (int kb = 0; kb < 8; kb++) {
        const float* wrow = sW + kb * 16 * 32 + cg;
        #pragma unroll
        for (int kk = 0; kk < 8; kk++) {
            float4 w = *(const float4*)(wrow + kk * 32);
            #pragma unroll
            for (int r = 0; r < 2; r++) {
                float4 aq = bufA[r][kk >> 2];
                float av = ((kk & 3) == 0) ? aq.x : ((kk & 3) == 1) ? aq.y
                         : ((kk & 3) == 2) ? aq.z : aq.w;
                acc[r][0] = fmaf(av, w.x, acc[r][0]);
                acc[r][1] = fmaf(av, w.y, acc[r][1]);
                acc[r][2] = fmaf(av, w.z, acc[r][2]);
                acc[r][3] = fmaf(av, w.w, acc[r][3]);
            }
        }
        if (kb < 7) {
            #pragma unroll
            for (int r = 0; r < 2; r++) {
                const float* ap = aptr(r, kb + 1);
                bufA[r][0] = *(const float4*)(ap + 0);
                bufA[r][1] = *(const float4*)(ap + 4);
            }
        }
        #pragma unroll
        for (int kk = 0; kk < 8; kk++) {
            float4 w = *(const float4*)(wrow + (8 + kk) * 32);
            #pragma unroll
            for (int r = 0; r < 2; r++) {
                float4 aq = bufB[r][kk >> 2];
                float av = ((kk & 3) == 0) ? aq.x : ((kk & 3) == 1) ? aq.y
                         : ((kk & 3) == 2) ? aq.z : aq.w;
                acc[r][0] = fmaf(av, w.x, acc[r][0]);
                acc[r][1] = fmaf(av, w.y, acc[r][1]);
                acc[r][2] = fmaf(av, w.z, acc[r][2]);
                acc[r][3] = fmaf(av, w.w, acc[r][3]);
            }
        }
        if (kb < 7) {
            #pragma unroll
            for (int r = 0; r < 2; r++) {
                const float* ap = aptr(r, kb + 1);
                bufB[r][0] = *(const float4*)(ap + 8);
                bufB[r][1] = *(const float4*)(ap + 12);
            }
        }
    }

    int cb = col0 + cg;
    float* Cb = C + (size_t)(cb >> 5) * ns * 32 + (cb & 31);
    #pragma unroll
    for (int r = 0; r < 2; r++) {
        int rr = rbase + r;
        if (rr < n) {
            float dsc = dinv[rr];
            *(float4*)(Cb + (size_t)rr * 32) =
                make_float4(acc[r][0] * dsc, acc[r][1] * dsc,
                            acc[r][2] * dsc, acc[r][3] * dsc);
        }
    }
}

// ---- Aggregation: 4 slices x 32ch, 8 nodes/wave x 8 lanes, 128B rows ------
// h holds pre-scaled rows (h*dinv[row]) blocked [4][ns][32]; row n is zeros.
// out[i] = relu( (sum_edges slice[src] + slice[i]) * dinv[i] + b )
__global__ __launch_bounds__(256) void agg_kernel(const float* __restrict__ h,
                                                  const int* __restrict__ row_ptr,
                                                  const unsigned short* __restrict__ csr,
                                                  const float* __restrict__ dinv,
                                                  const float* __restrict__ bias,
                                                  float* __restrict__ out,
                                                  int n, int ns) {
    int p = blockIdx.x & 3;
    int i = (blockIdx.x >> 2) * 32 + (threadIdx.x >> 3);
    int q = threadIdx.x & 7;
    bool valid = (i < n);
    int iv = valid ? i : 0;

    const float* slice  = h   + (size_t)p * ns * 32;
    float*       oslice = out + (size_t)p * ns * 32;

    int beg = row_ptr[iv];
    int end = valid ? row_ptr[iv + 1] : beg;
    int qoff = q << 2;

    float4 acc = make_float4(0.f, 0.f, 0.f, 0.f);

    int e = beg;
    int s0 = (int)__builtin_nontemporal_load(csr + e);
    int s1 = (int)__builtin_nontemporal_load(csr + e + 1);
    int s2 = (int)__builtin_nontemporal_load(csr + e + 2);
    int s3 = (int)__builtin_nontemporal_load(csr + e + 3);

    while (__any(e < end)) {
        int en = e + 4;
        int t0 = (int)__builtin_nontemporal_load(csr + en);
        int t1 = (int)__builtin_nontemporal_load(csr + en + 1);
        int t2 = (int)__builtin_nontemporal_load(csr + en + 2);
        int t3 = (int)__builtin_nontemporal_load(csr + en + 3);

        int g0 = (e     < end) ? s0 : n;
        int g1 = (e + 1 < end) ? s1 : n;
        int g2 = (e + 2 < end) ? s2 : n;
        int g3 = (e + 3 < end) ? s3 : n;

        float4 v0 = *(const float4*)(slice + ((size_t)g0 << 5) + qoff);
        float4 v1 = *(const float4*)(slice + ((size_t)g1 << 5) + qoff);
        float4 v2 = *(const float4*)(slice + ((size_t)g2 << 5) + qoff);
        float4 v3 = *(const float4*)(slice + ((size_t)g3 << 5) + qoff);

        acc.x += v0.x; acc.y += v0.y; acc.z += v0.z; acc.w += v0.w;
        acc.x += v1.x; acc.y += v1.y; acc.z += v1.z; acc.w += v1.w;
        acc.x += v2.x; acc.y += v2.y; acc.z += v2.z; acc.w += v2.w;
        acc.x += v3.x; acc.y += v3.y; acc.z += v3.z; acc.w += v3.w;

        e = en; s0 = t0; s1 = t1; s2 = t2; s3 = t3;
    }

    if (valid) {
        float di = dinv[i];
        float4 self = *(const float4*)(slice + ((size_t)i << 5) + qoff);
        float4 b4   = *(const float4*)(bias + p * 32 + qoff);
        float4 o;
        o.x = fmaxf(fmaf(acc.x + self.x, di, b4.x), 0.f);
        o.y = fmaxf(fmaf(acc.y + self.y, di, b4.y), 0.f);
        o.z = fmaxf(fmaf(acc.z + self.z, di, b4.z), 0.f);
        o.w = fmaxf(fmaf(acc.w + self.w, di, b4.w), 0.f);
        *(float4*)(oslice + ((size_t)i << 5) + qoff) = o;
    }
}

// ---- pool stage 1: deterministic fp64 partials, one slot per (g,s) --------
__global__ __launch_bounds__(128) void pool_partial_kernel(const float* __restrict__ h,
                                                           const int* __restrict__ batch,
                                                           double* __restrict__ partials,
                                                           int n, int ns, int S) {
    int g = blockIdx.x / S;
    int s = blockIdx.x % S;
    int c = threadIdx.x;
    const float* hb = h + (size_t)(c >> 5) * ns * 32 + (c & 31);

    int lo = 0, hi = n;
    while (lo < hi) { int mid = (lo + hi) >> 1; if (batch[mid] < g) lo = mid + 1; else hi = mid; }
    int start = lo;
    lo = start; hi = n;
    while (lo < hi) { int mid = (lo + hi) >> 1; if (batch[mid] < g + 1) lo = mid + 1; else hi = mid; }
    int end = lo;

    int cnt = end - start;
    int per = (cnt + S - 1) / S;
    int rs = start + s * per;
    int re = rs + per; if (re > end) re = end;

    double a0 = 0.0, a1 = 0.0, a2 = 0.0, a3 = 0.0;
    int r = rs;
    for (; r + 4 <= re; r += 4) {
        a0 += (double)hb[(size_t)(r + 0) * 32];
        a1 += (double)hb[(size_t)(r + 1) * 32];
        a2 += (double)hb[(size_t)(r + 2) * 32];
        a3 += (double)hb[(size_t)(r + 3) * 32];
    }
    for (; r < re; r++) a0 += (double)hb[(size_t)r * 32];
    partials[(size_t)(g * S + s) * 128 + c] = (a0 + a1) + (a2 + a3);
}

// ---- pool stage 2: reduce S partials, mean + FC(128->1), fp64 -------------
__global__ __launch_bounds__(128) void pool_fc_final_kernel(const double* __restrict__ partials,
                                                            const int* __restrict__ batch,
                                                            const float* __restrict__ Wfc,
                                                            const float* __restrict__ bfc,
                                                            float* __restrict__ out,
                                                            int n, int S) {
    int g = blockIdx.x;
    int c = threadIdx.x;

    int lo = 0, hi = n;
    while (lo < hi) { int mid = (lo + hi) >> 1; if (batch[mid] < g) lo = mid + 1; else hi = mid; }
    int start = lo;
    lo = start; hi = n;
    while (lo < hi) { int mid = (lo + hi) >> 1; if (batch[mid] < g + 1) lo = mid + 1; else hi = mid; }
    int cnt = lo - start;

    double sum = 0.0;
    for (int s = 0; s < S; s++) sum += partials[(size_t)(g * S + s) * 128 + c];
    double mean = sum / (double)(cnt > 0 ? cnt : 1);
    double v = mean * (double)Wfc[c];

    __shared__ double red[128];
    red[c] = v;
    __syncthreads();
    for (int off = 64; off > 0; off >>= 1) {
        if (c < off) red[c] += red[c + off];
        __syncthreads();
    }
    if (c == 0) out[g] = (float)(red[0] + (double)bfc[0]);
}

// ---------------------------------------------------------------------------
extern "C" void kernel_launch(void* const* d_in, const int* in_sizes, int n_in,
                              void* d_out, int out_size, void* d_ws, size_t ws_size,
                              hipStream_t stream) {
    const float* x          = (const float*)d_in[0];
    const int*   edge_index = (const int*)d_in[1];
    const int*   batch      = (const int*)d_in[2];
    const float* W1  = (const float*)d_in[3];
    const float* b1  = (const float*)d_in[4];
    const float* W2  = (const float*)d_in[5];
    const float* b2  = (const float*)d_in[6];
    const float* Wfc = (const float*)d_in[7];
    const float* bfc = (const float*)d_in[8];
    float* out = (float*)d_out;

    const int N = in_sizes[2];       // 50000
    const int E = in_sizes[1] / 2;   // 1600000
    const int G = out_size;          // 128 graphs
    const int NS = N + 1;            // slice stride in rows (pad row = zeros)

    const int* e_src = edge_index;
    const int* e_dst = edge_index + E;

    char* p = (char*)d_ws;
    auto alloc = [&](size_t bytes) {
        void* r = (void*)p;
        p += (bytes + 255) & ~(size_t)255;
        return r;
    };
    const int S = 8;
    const int NB = (N + 255) / 256;     // scan blocks (196)
    float*          h0        = (float*)alloc((size_t)NS * 128 * 4);
    float*          h1        = (float*)alloc((size_t)NS * 128 * 4);
    unsigned short* csr       = (unsigned short*)alloc(((size_t)E + 1024) * 2);
    unsigned int*   buckets   = (unsigned int*)alloc((size_t)8 * CAPB * 4);
    int*            bcount    = (int*)  alloc(8 * 4);
    int*            row       = (int*)  alloc((size_t)(N + 1) * 4);
    int*            deg       = (int*)  alloc((size_t)N * 4);
    int*            fill      = (int*)  alloc((size_t)N * 4);
    int*            bsum      = (int*)  alloc((size_t)NB * 4);
    int*            boff      = (int*)  alloc((size_t)NB * 4);
    float*          dinv      = (float*)alloc((size_t)N * 4);
    double*         partials  = (double*)alloc((size_t)G * S * 128 * 8);
    (void)ws_size; (void)n_in;

    hipMemsetAsync(deg,    0, (size_t)N * 4, stream);
    hipMemsetAsync(fill,   0, (size_t)N * 4, stream);
    hipMemsetAsync(bcount, 0, 8 * 4, stream);

    int tb = 256;
    bucket_count_kernel<<<(E + tb - 1) / tb, tb, 0, stream>>>(e_src, e_dst, deg,
                                                              buckets, bcount, E, N);
    dinv_kernel<<<(N + tb - 1) / tb, tb, 0, stream>>>(deg, dinv, h0, h1, N, NS);
    scan_blocksum_kernel<<<NB, 256, 0, stream>>>(deg, bsum, N);
    scan_bsum_kernel<<<1, 1024, 0, stream>>>(bsum, boff, NB);
    scan_final_kernel<<<NB, 256, 0, stream>>>(deg, boff, row, N);
    csr_fill_kernel<<<1024, tb, 0, stream>>>(buckets, bcount, row, fill, csr);

    int gemm_blocks = 4 * ((N + 63) / 64);
    int agg_blocks  = 4 * ((N + 31) / 32);

    gemm_kernel<<<gemm_blocks, 256, 0, stream>>>(x, W1, dinv, h1, N, NS, 0);
    agg_kernel<<<agg_blocks, 256, 0, stream>>>(h1, row, csr, dinv, b1, h0, N, NS);

    for (int l = 0; l < 3; l++) {
        gemm_kernel<<<gemm_blocks, 256, 0, stream>>>(h0, W2, dinv, h1, N, NS, 1);
        agg_kernel<<<agg_blocks, 256, 0, stream>>>(h1, row, csr, dinv, b2, h0, N, NS);
    }

    pool_partial_kernel<<<G * S, 128, 0, stream>>>(h0, batch, partials, N, NS, S);
    pool_fc_final_kernel<<<G, 128, 0, stream>>>(partials, batch, Wfc, bfc, out, N, S);
}

// Round 15
// 786.747 us; speedup vs baseline: 3.8344x; 3.8344x over previous
//
#include <hip/hip_runtime.h>
#include <hip/hip_bf16.h>

// ---------------------------------------------------------------------------
// GCNRegression: 4x (GEMM 128x128 + symmetric-norm aggregation + ReLU),
// then global mean pool (128 graphs) + FC(128->1).
//
// R14 notes: bucket build catastrophically slow (2300us: wave-serialized
// return-dependent atomics on 8 counters in one line) -> REVERTED to proven
// single-pass count_deg + XCD-partitioned csr_fill (73us, R13-measured).
// GEMM: 2x4 -> 4x4 thread tile (128-row blocks): per-kb 256 FMA : 16
// LDS-b128 (VALU-dominated, was near-LDS-bound at 128:16).
// ---------------------------------------------------------------------------

// ---- degree histogram (single pass, int4 reads) ---------------------------
__global__ void count_deg_kernel(const int* __restrict__ dst, int* __restrict__ deg, int E) {
    int i = blockIdx.x * blockDim.x + threadIdx.x;
    int e = i * 4;
    if (e + 3 < E) {
        int4 d = *(const int4*)(dst + e);
        atomicAdd(&deg[d.x], 1);
        atomicAdd(&deg[d.y], 1);
        atomicAdd(&deg[d.z], 1);
        atomicAdd(&deg[d.w], 1);
    } else {
        for (; e < E; e++) atomicAdd(&deg[dst[e]], 1);
    }
}

// ---- dinv = 1/sqrt(deg+1); zero the pad rows of h0/h1 (4 slices x 32ch) ---
__global__ void dinv_kernel(const int* __restrict__ deg, float* __restrict__ dinv,
                            float* __restrict__ h0, float* __restrict__ h1,
                            int n, int ns) {
    int i = blockIdx.x * blockDim.x + threadIdx.x;
    if (i < n) dinv[i] = (float)(1.0 / sqrt((double)(deg[i] + 1)));
    if (i < 128) {                       // 4 slices x 32 channels pad row
        int p = i >> 5, c = i & 31;
        size_t off = (size_t)p * ns * 32 + (size_t)n * 32 + c;
        h0[off] = 0.f;
        h1[off] = 0.f;
    }
}

// ---- multi-block exclusive scan (3 phases) --------------------------------
__global__ void scan_blocksum_kernel(const int* __restrict__ cnt, int* __restrict__ bsum,
                                     int n2) {
    __shared__ int red[256];
    int t = threadIdx.x;
    int i = blockIdx.x * 256 + t;
    red[t] = (i < n2) ? cnt[i] : 0;
    __syncthreads();
    for (int off = 128; off > 0; off >>= 1) {
        if (t < off) red[t] += red[t + off];
        __syncthreads();
    }
    if (t == 0) bsum[blockIdx.x] = red[0];
}

__global__ __launch_bounds__(1024) void scan_bsum_kernel(const int* __restrict__ bsum,
                                                         int* __restrict__ boff, int nb) {
    __shared__ int s[1024];
    int t = threadIdx.x;
    int v = (t < nb) ? bsum[t] : 0;
    s[t] = v;
    __syncthreads();
    for (int off = 1; off < 1024; off <<= 1) {
        int u = (t >= off) ? s[t - off] : 0;
        __syncthreads();
        s[t] += u;
        __syncthreads();
    }
    if (t < nb) boff[t] = s[t] - v;
}

__global__ void scan_final_kernel(const int* __restrict__ cnt, const int* __restrict__ boff,
                                  int* __restrict__ row, int n2) {
    __shared__ int s[256];
    int t = threadIdx.x;
    int b = blockIdx.x;
    int i = b * 256 + t;
    int v = (i < n2) ? cnt[i] : 0;
    s[t] = v;
    __syncthreads();
    for (int off = 1; off < 256; off <<= 1) {
        int u = (t >= off) ? s[t - off] : 0;
        __syncthreads();
        s[t] += u;
        __syncthreads();
    }
    int incl = s[t];
    int base = boff[b];
    if (i < n2) row[i] = base + incl - v;
    if (i == n2 - 1) row[n2] = base + incl;
}

// ---- CSR fill (uint16 src), XCD-range-partitioned (proven, 73us) ----------
__global__ __launch_bounds__(256) void csr_fill_kernel(const int* __restrict__ src,
                                                       const int* __restrict__ dst,
                                                       const int* __restrict__ row,
                                                       int* __restrict__ fill,
                                                       unsigned short* __restrict__ csr,
                                                       int E, int N) {
    int g  = blockIdx.x & 7;
    int gb = blockIdx.x >> 3;
    int group_blocks = gridDim.x >> 3;
    int R  = (N + 7) >> 3;
    int lo = g * R;
    int hi = lo + R; if (hi > N) hi = N;

    int tig    = gb * blockDim.x + threadIdx.x;
    int stride = group_blocks * blockDim.x;
    int nq = (E + 3) >> 2;

    for (int q = tig; q < nq; q += stride) {
        int e = q * 4;
        if (e + 3 < E) {
            int4 d = *(const int4*)(dst + e);
            if (d.x >= lo && d.x < hi) {
                int pos = row[d.x] + atomicAdd(&fill[d.x], 1);
                csr[pos] = (unsigned short)src[e + 0];
            }
            if (d.y >= lo && d.y < hi) {
                int pos = row[d.y] + atomicAdd(&fill[d.y], 1);
                csr[pos] = (unsigned short)src[e + 1];
            }
            if (d.z >= lo && d.z < hi) {
                int pos = row[d.z] + atomicAdd(&fill[d.z], 1);
                csr[pos] = (unsigned short)src[e + 2];
            }
            if (d.w >= lo && d.w < hi) {
                int pos = row[d.w] + atomicAdd(&fill[d.w], 1);
                csr[pos] = (unsigned short)src[e + 3];
            }
        } else {
            for (; e < E; e++) {
                int d = dst[e];
                if (d >= lo && d < hi) {
                    int pos = row[d] + atomicAdd(&fill[d], 1);
                    csr[pos] = (unsigned short)src[e];
                }
            }
        }
    }
}

// ---- GEMM: C = (A @ W) * dinv[row], C channel-blocked [4][ns][32] ---------
// 128 rows x 32 cols per 256-thread block; W quarter (16KB) in LDS.
// Per thread 4 rows x 4 cols (256 FMA : 16 LDS-b128 per kb). A addresses
// recomputed per 16-k chunk (kb):
//   flat [n][128]:       A + rr*128 + kb*16
//   blocked [4][ns][32]: A + ((kb>>1)*ns + rr)*32 + (kb&1)*16
__global__ __launch_bounds__(256) void gemm_kernel(const float* __restrict__ A,
                                                   const float* __restrict__ W,
                                                   const float* __restrict__ dinv,
                                                   float* __restrict__ C, int n, int ns,
                                                   int a_blocked) {
    __shared__ float sW[128 * 32];
    int t = threadIdx.x;
    int col0 = (blockIdx.x & 3) * 32;
    int row0 = (blockIdx.x >> 2) * 128;

    #pragma unroll
    for (int i = 0; i < 4; i++) {
        int fidx = t + 256 * i;            // 1024 float4
        int k  = fidx >> 3;
        int c4 = fidx & 7;
        *(float4*)(sW + k * 32 + c4 * 4) =
            *(const float4*)(W + (size_t)k * 128 + col0 + c4 * 4);
    }
    __syncthreads();

    int cg = (t & 7) * 4;          // 4 cols within the 32-col tile
    int rg = (t >> 3) * 4;         // 4 rows
    int rbase = row0 + rg;

    int rr_[4];
    #pragma unroll
    for (int r = 0; r < 4; r++) {
        int rr = rbase + r; if (rr > n - 1) rr = n - 1;   // clamp (store guarded)
        rr_[r] = rr;
    }
    auto aptr = [&](int r, int kb) -> const float* {
        return a_blocked
            ? (A + ((size_t)(kb >> 1) * ns + rr_[r]) * 32 + ((kb & 1) * 16))
            : (A + (size_t)rr_[r] * 128 + kb * 16);
    };

    float acc[4][4];
    #pragma unroll
    for (int r = 0; r < 4; r++)
        #pragma unroll
        for (int c = 0; c < 4; c++) acc[r][c] = 0.f;

    // bufA holds k = kb*16+0..7, bufB holds k = kb*16+8..15
    float4 bufA[4][2], bufB[4][2];
    #pragma unroll
    for (int r = 0; r < 4; r++) {
        const float* ap = aptr(r, 0);
        bufA[r][0] = *(const float4*)(ap + 0);
        bufA[r][1] = *(const float4*)(ap + 4);
        bufB[r][0] = *(const float4*)(ap + 8);
        bufB[r][1] = *(const float4*)(ap + 12);
    }

    #pragma unroll 1
    for (int kb = 0; kb < 8; kb++) {
        const float* wrow = sW + kb * 16 * 32 + cg;
        #pragma unroll
        for (int kk = 0; kk < 8; kk++) {
            float4 w = *(const float4*)(wrow + kk * 32);
            #pragma unroll
            for (int r = 0; r < 4; r++) {
                float4 aq = bufA[r][kk >> 2];
                float av = ((kk & 3) == 0) ? aq.x : ((kk & 3) == 1) ? aq.y
                         : ((kk & 3) == 2) ? aq.z : aq.w;
                acc[r][0] = fmaf(av, w.x, acc[r][0]);
                acc[r][1] = fmaf(av, w.y, acc[r][1]);
                acc[r][2] = fmaf(av, w.z, acc[r][2]);
                acc[r][3] = fmaf(av, w.w, acc[r][3]);
            }
        }
        if (kb < 7) {   // prefetch next kb first half (used after bufB compute)
            #pragma unroll
            for (int r = 0; r < 4; r++) {
                const float* ap = aptr(r, kb + 1);
                bufA[r][0] = *(const float4*)(ap + 0);
                bufA[r][1] = *(const float4*)(ap + 4);
            }
        }
        #pragma unroll
        for (int kk = 0; kk < 8; kk++) {
            float4 w = *(const float4*)(wrow + (8 + kk) * 32);
            #pragma unroll
            for (int r = 0; r < 4; r++) {
                float4 aq = bufB[r][kk >> 2];
                float av = ((kk & 3) == 0) ? aq.x : ((kk & 3) == 1) ? aq.y
                         : ((kk & 3) == 2) ? aq.z : aq.w;
                acc[r][0] = fmaf(av, w.x, acc[r][0]);
                acc[r][1] = fmaf(av, w.y, acc[r][1]);
                acc[r][2] = fmaf(av, w.z, acc[r][2]);
                acc[r][3] = fmaf(av, w.w, acc[r][3]);
            }
        }
        if (kb < 7) {
            #pragma unroll
            for (int r = 0; r < 4; r++) {
                const float* ap = aptr(r, kb + 1);
                bufB[r][0] = *(const float4*)(ap + 8);
                bufB[r][1] = *(const float4*)(ap + 12);
            }
        }
    }

    int cb = col0 + cg;
    float* Cb = C + (size_t)(cb >> 5) * ns * 32 + (cb & 31);
    #pragma unroll
    for (int r = 0; r < 4; r++) {
        int rr = rbase + r;
        if (rr < n) {
            float dsc = dinv[rr];
            *(float4*)(Cb + (size_t)rr * 32) =
                make_float4(acc[r][0] * dsc, acc[r][1] * dsc,
                            acc[r][2] * dsc, acc[r][3] * dsc);
        }
    }
}

// ---- Aggregation: 4 slices x 32ch, 8 nodes/wave x 8 lanes, 128B rows ------
// h holds pre-scaled rows (h*dinv[row]) blocked [4][ns][32]; row n is zeros.
// out[i] = relu( (sum_edges slice[src] + slice[i]) * dinv[i] + b )
__global__ __launch_bounds__(256) void agg_kernel(const float* __restrict__ h,
                                                  const int* __restrict__ row_ptr,
                                                  const unsigned short* __restrict__ csr,
                                                  const float* __restrict__ dinv,
                                                  const float* __restrict__ bias,
                                                  float* __restrict__ out,
                                                  int n, int ns) {
    int p = blockIdx.x & 3;
    int i = (blockIdx.x >> 2) * 32 + (threadIdx.x >> 3);
    int q = threadIdx.x & 7;
    bool valid = (i < n);
    int iv = valid ? i : 0;

    const float* slice  = h   + (size_t)p * ns * 32;
    float*       oslice = out + (size_t)p * ns * 32;

    int beg = row_ptr[iv];
    int end = valid ? row_ptr[iv + 1] : beg;
    int qoff = q << 2;

    float4 acc = make_float4(0.f, 0.f, 0.f, 0.f);

    int e = beg;
    int s0 = (int)__builtin_nontemporal_load(csr + e);
    int s1 = (int)__builtin_nontemporal_load(csr + e + 1);
    int s2 = (int)__builtin_nontemporal_load(csr + e + 2);
    int s3 = (int)__builtin_nontemporal_load(csr + e + 3);

    while (__any(e < end)) {
        int en = e + 4;
        int t0 = (int)__builtin_nontemporal_load(csr + en);
        int t1 = (int)__builtin_nontemporal_load(csr + en + 1);
        int t2 = (int)__builtin_nontemporal_load(csr + en + 2);
        int t3 = (int)__builtin_nontemporal_load(csr + en + 3);

        int g0 = (e     < end) ? s0 : n;
        int g1 = (e + 1 < end) ? s1 : n;
        int g2 = (e + 2 < end) ? s2 : n;
        int g3 = (e + 3 < end) ? s3 : n;

        float4 v0 = *(const float4*)(slice + ((size_t)g0 << 5) + qoff);
        float4 v1 = *(const float4*)(slice + ((size_t)g1 << 5) + qoff);
        float4 v2 = *(const float4*)(slice + ((size_t)g2 << 5) + qoff);
        float4 v3 = *(const float4*)(slice + ((size_t)g3 << 5) + qoff);

        acc.x += v0.x; acc.y += v0.y; acc.z += v0.z; acc.w += v0.w;
        acc.x += v1.x; acc.y += v1.y; acc.z += v1.z; acc.w += v1.w;
        acc.x += v2.x; acc.y += v2.y; acc.z += v2.z; acc.w += v2.w;
        acc.x += v3.x; acc.y += v3.y; acc.z += v3.z; acc.w += v3.w;

        e = en; s0 = t0; s1 = t1; s2 = t2; s3 = t3;
    }

    if (valid) {
        float di = dinv[i];
        float4 self = *(const float4*)(slice + ((size_t)i << 5) + qoff);
        float4 b4   = *(const float4*)(bias + p * 32 + qoff);
        float4 o;
        o.x = fmaxf(fmaf(acc.x + self.x, di, b4.x), 0.f);
        o.y = fmaxf(fmaf(acc.y + self.y, di, b4.y), 0.f);
        o.z = fmaxf(fmaf(acc.z + self.z, di, b4.z), 0.f);
        o.w = fmaxf(fmaf(acc.w + self.w, di, b4.w), 0.f);
        *(float4*)(oslice + ((size_t)i << 5) + qoff) = o;
    }
}

// ---- pool stage 1: deterministic fp64 partials, one slot per (g,s) --------
__global__ __launch_bounds__(128) void pool_partial_kernel(const float* __restrict__ h,
                                                           const int* __restrict__ batch,
                                                           double* __restrict__ partials,
                                                           int n, int ns, int S) {
    int g = blockIdx.x / S;
    int s = blockIdx.x % S;
    int c = threadIdx.x;
    const float* hb = h + (size_t)(c >> 5) * ns * 32 + (c & 31);

    int lo = 0, hi = n;
    while (lo < hi) { int mid = (lo + hi) >> 1; if (batch[mid] < g) lo = mid + 1; else hi = mid; }
    int start = lo;
    lo = start; hi = n;
    while (lo < hi) { int mid = (lo + hi) >> 1; if (batch[mid] < g + 1) lo = mid + 1; else hi = mid; }
    int end = lo;

    int cnt = end - start;
    int per = (cnt + S - 1) / S;
    int rs = start + s * per;
    int re = rs + per; if (re > end) re = end;

    double a0 = 0.0, a1 = 0.0, a2 = 0.0, a3 = 0.0;
    int r = rs;
    for (; r + 4 <= re; r += 4) {
        a0 += (double)hb[(size_t)(r + 0) * 32];
        a1 += (double)hb[(size_t)(r + 1) * 32];
        a2 += (double)hb[(size_t)(r + 2) * 32];
        a3 += (double)hb[(size_t)(r + 3) * 32];
    }
    for (; r < re; r++) a0 += (double)hb[(size_t)r * 32];
    partials[(size_t)(g * S + s) * 128 + c] = (a0 + a1) + (a2 + a3);
}

// ---- pool stage 2: reduce S partials, mean + FC(128->1), fp64 -------------
__global__ __launch_bounds__(128) void pool_fc_final_kernel(const double* __restrict__ partials,
                                                            const int* __restrict__ batch,
                                                            const float* __restrict__ Wfc,
                                                            const float* __restrict__ bfc,
                                                            float* __restrict__ out,
                                                            int n, int S) {
    int g = blockIdx.x;
    int c = threadIdx.x;

    int lo = 0, hi = n;
    while (lo < hi) { int mid = (lo + hi) >> 1; if (batch[mid] < g) lo = mid + 1; else hi = mid; }
    int start = lo;
    lo = start; hi = n;
    while (lo < hi) { int mid = (lo + hi) >> 1; if (batch[mid] < g + 1) lo = mid + 1; else hi = mid; }
    int cnt = lo - start;

    double sum = 0.0;
    for (int s = 0; s < S; s++) sum += partials[(size_t)(g * S + s) * 128 + c];
    double mean = sum / (double)(cnt > 0 ? cnt : 1);
    double v = mean * (double)Wfc[c];

    __shared__ double red[128];
    red[c] = v;
    __syncthreads();
    for (int off = 64; off > 0; off >>= 1) {
        if (c < off) red[c] += red[c + off];
        __syncthreads();
    }
    if (c == 0) out[g] = (float)(red[0] + (double)bfc[0]);
}

// ---------------------------------------------------------------------------
extern "C" void kernel_launch(void* const* d_in, const int* in_sizes, int n_in,
                              void* d_out, int out_size, void* d_ws, size_t ws_size,
                              hipStream_t stream) {
    const float* x          = (const float*)d_in[0];
    const int*   edge_index = (const int*)d_in[1];
    const int*   batch      = (const int*)d_in[2];
    const float* W1  = (const float*)d_in[3];
    const float* b1  = (const float*)d_in[4];
    const float* W2  = (const float*)d_in[5];
    const float* b2  = (const float*)d_in[6];
    const float* Wfc = (const float*)d_in[7];
    const float* bfc = (const float*)d_in[8];
    float* out = (float*)d_out;

    const int N = in_sizes[2];       // 50000
    const int E = in_sizes[1] / 2;   // 1600000
    const int G = out_size;          // 128 graphs
    const int NS = N + 1;            // slice stride in rows (pad row = zeros)

    const int* e_src = edge_index;
    const int* e_dst = edge_index + E;

    char* p = (char*)d_ws;
    auto alloc = [&](size_t bytes) {
        void* r = (void*)p;
        p += (bytes + 255) & ~(size_t)255;
        return r;
    };
    const int S = 8;
    const int NB = (N + 255) / 256;     // scan blocks
    float*          h0        = (float*)alloc((size_t)NS * 128 * 4);
    float*          h1        = (float*)alloc((size_t)NS * 128 * 4);
    unsigned short* csr       = (unsigned short*)alloc(((size_t)E + 1024) * 2);
    int*            row       = (int*)  alloc((size_t)(N + 1) * 4);
    int*            deg       = (int*)  alloc((size_t)N * 4);
    int*            fill      = (int*)  alloc((size_t)N * 4);
    int*            bsum      = (int*)  alloc((size_t)NB * 4);
    int*            boff      = (int*)  alloc((size_t)NB * 4);
    float*          dinv      = (float*)alloc((size_t)N * 4);
    double*         partials  = (double*)alloc((size_t)G * S * 128 * 8);
    (void)ws_size; (void)n_in;

    hipMemsetAsync(deg,  0, (size_t)N * 4, stream);
    hipMemsetAsync(fill, 0, (size_t)N * 4, stream);

    int tb = 256;
    int e4 = (E + 3) / 4;
    count_deg_kernel<<<(e4 + tb - 1) / tb, tb, 0, stream>>>(e_dst, deg, E);
    dinv_kernel<<<(N + tb - 1) / tb, tb, 0, stream>>>(deg, dinv, h0, h1, N, NS);
    scan_blocksum_kernel<<<NB, 256, 0, stream>>>(deg, bsum, N);
    scan_bsum_kernel<<<1, 1024, 0, stream>>>(bsum, boff, NB);
    scan_final_kernel<<<NB, 256, 0, stream>>>(deg, boff, row, N);
    csr_fill_kernel<<<1024, tb, 0, stream>>>(e_src, e_dst, row, fill, csr, E, N);

    int gemm_blocks = 4 * ((N + 127) / 128);
    int agg_blocks  = 4 * ((N + 31) / 32);

    gemm_kernel<<<gemm_blocks, 256, 0, stream>>>(x, W1, dinv, h1, N, NS, 0);
    agg_kernel<<<agg_blocks, 256, 0, stream>>>(h1, row, csr, dinv, b1, h0, N, NS);

    for (int l = 0; l < 3; l++) {
        gemm_kernel<<<gemm_blocks, 256, 0, stream>>>(h0, W2, dinv, h1, N, NS, 1);
        agg_kernel<<<agg_blocks, 256, 0, stream>>>(h1, row, csr, dinv, b2, h0, N, NS);
    }

    pool_partial_kernel<<<G * S, 128, 0, stream>>>(h0, batch, partials, N, NS, S);
    pool_fc_final_kernel<<<G, 128, 0, stream>>>(partials, batch, Wfc, bfc, out, N, S);
}

// Round 16
// 765.798 us; speedup vs baseline: 3.9393x; 1.0274x over previous
//
#include <hip/hip_runtime.h>
#include <hip/hip_bf16.h>

// ---------------------------------------------------------------------------
// GCNRegression: 4x (GEMM 128x128 + symmetric-norm aggregation + ReLU),
// then global mean pool (128 graphs) + FC(128->1).
//
// R15 notes: 4x4 reg tile was neutral -> gemm is A-load latency-bound, not
// issue-bound. GEMM v3: cooperative LDS A-staging (128x16 tile, 8KB,
// double-buffered; coalesced copy), compute entirely from LDS. Rows owned
// strided ((t>>3)+32j) -> 2-way LDS aliasing (free). One barrier per kb.
// Everything else frozen (attribution).
// ---------------------------------------------------------------------------

// ---- degree histogram (single pass, int4 reads) ---------------------------
__global__ void count_deg_kernel(const int* __restrict__ dst, int* __restrict__ deg, int E) {
    int i = blockIdx.x * blockDim.x + threadIdx.x;
    int e = i * 4;
    if (e + 3 < E) {
        int4 d = *(const int4*)(dst + e);
        atomicAdd(&deg[d.x], 1);
        atomicAdd(&deg[d.y], 1);
        atomicAdd(&deg[d.z], 1);
        atomicAdd(&deg[d.w], 1);
    } else {
        for (; e < E; e++) atomicAdd(&deg[dst[e]], 1);
    }
}

// ---- dinv = 1/sqrt(deg+1); zero the pad rows of h0/h1 (4 slices x 32ch) ---
__global__ void dinv_kernel(const int* __restrict__ deg, float* __restrict__ dinv,
                            float* __restrict__ h0, float* __restrict__ h1,
                            int n, int ns) {
    int i = blockIdx.x * blockDim.x + threadIdx.x;
    if (i < n) dinv[i] = (float)(1.0 / sqrt((double)(deg[i] + 1)));
    if (i < 128) {                       // 4 slices x 32 channels pad row
        int p = i >> 5, c = i & 31;
        size_t off = (size_t)p * ns * 32 + (size_t)n * 32 + c;
        h0[off] = 0.f;
        h1[off] = 0.f;
    }
}

// ---- multi-block exclusive scan (3 phases) --------------------------------
__global__ void scan_blocksum_kernel(const int* __restrict__ cnt, int* __restrict__ bsum,
                                     int n2) {
    __shared__ int red[256];
    int t = threadIdx.x;
    int i = blockIdx.x * 256 + t;
    red[t] = (i < n2) ? cnt[i] : 0;
    __syncthreads();
    for (int off = 128; off > 0; off >>= 1) {
        if (t < off) red[t] += red[t + off];
        __syncthreads();
    }
    if (t == 0) bsum[blockIdx.x] = red[0];
}

__global__ __launch_bounds__(1024) void scan_bsum_kernel(const int* __restrict__ bsum,
                                                         int* __restrict__ boff, int nb) {
    __shared__ int s[1024];
    int t = threadIdx.x;
    int v = (t < nb) ? bsum[t] : 0;
    s[t] = v;
    __syncthreads();
    for (int off = 1; off < 1024; off <<= 1) {
        int u = (t >= off) ? s[t - off] : 0;
        __syncthreads();
        s[t] += u;
        __syncthreads();
    }
    if (t < nb) boff[t] = s[t] - v;
}

__global__ void scan_final_kernel(const int* __restrict__ cnt, const int* __restrict__ boff,
                                  int* __restrict__ row, int n2) {
    __shared__ int s[256];
    int t = threadIdx.x;
    int b = blockIdx.x;
    int i = b * 256 + t;
    int v = (i < n2) ? cnt[i] : 0;
    s[t] = v;
    __syncthreads();
    for (int off = 1; off < 256; off <<= 1) {
        int u = (t >= off) ? s[t - off] : 0;
        __syncthreads();
        s[t] += u;
        __syncthreads();
    }
    int incl = s[t];
    int base = boff[b];
    if (i < n2) row[i] = base + incl - v;
    if (i == n2 - 1) row[n2] = base + incl;
}

// ---- CSR fill (uint16 src), XCD-range-partitioned (proven) ----------------
__global__ __launch_bounds__(256) void csr_fill_kernel(const int* __restrict__ src,
                                                       const int* __restrict__ dst,
                                                       const int* __restrict__ row,
                                                       int* __restrict__ fill,
                                                       unsigned short* __restrict__ csr,
                                                       int E, int N) {
    int g  = blockIdx.x & 7;
    int gb = blockIdx.x >> 3;
    int group_blocks = gridDim.x >> 3;
    int R  = (N + 7) >> 3;
    int lo = g * R;
    int hi = lo + R; if (hi > N) hi = N;

    int tig    = gb * blockDim.x + threadIdx.x;
    int stride = group_blocks * blockDim.x;
    int nq = (E + 3) >> 2;

    for (int q = tig; q < nq; q += stride) {
        int e = q * 4;
        if (e + 3 < E) {
            int4 d = *(const int4*)(dst + e);
            if (d.x >= lo && d.x < hi) {
                int pos = row[d.x] + atomicAdd(&fill[d.x], 1);
                csr[pos] = (unsigned short)src[e + 0];
            }
            if (d.y >= lo && d.y < hi) {
                int pos = row[d.y] + atomicAdd(&fill[d.y], 1);
                csr[pos] = (unsigned short)src[e + 1];
            }
            if (d.z >= lo && d.z < hi) {
                int pos = row[d.z] + atomicAdd(&fill[d.z], 1);
                csr[pos] = (unsigned short)src[e + 2];
            }
            if (d.w >= lo && d.w < hi) {
                int pos = row[d.w] + atomicAdd(&fill[d.w], 1);
                csr[pos] = (unsigned short)src[e + 3];
            }
        } else {
            for (; e < E; e++) {
                int d = dst[e];
                if (d >= lo && d < hi) {
                    int pos = row[d] + atomicAdd(&fill[d], 1);
                    csr[pos] = (unsigned short)src[e];
                }
            }
        }
    }
}

// ---- GEMM v3: C = (A @ W) * dinv[row], C channel-blocked [4][ns][32] ------
// 128 rows x 32 cols per 256-thread block. LDS: W quarter (16KB, once) +
// A-tile 128x16 double-buffered (2x8KB). Inner loop reads ONLY LDS.
// Thread owns rows (t>>3)+32j (j=0..3) x 4 cols (t&7)*4.
// A source addresses per 16-k chunk kb:
//   flat [n][128]:       A + rr*128 + kb*16
//   blocked [4][ns][32]: A + ((kb>>1)*ns + rr)*32 + (kb&1)*16
__global__ __launch_bounds__(256) void gemm_kernel(const float* __restrict__ A,
                                                   const float* __restrict__ W,
                                                   const float* __restrict__ dinv,
                                                   float* __restrict__ C, int n, int ns,
                                                   int a_blocked) {
    __shared__ float sW[128 * 32];
    __shared__ float sA[2][128 * 16];
    int t = threadIdx.x;
    int col0 = (blockIdx.x & 3) * 32;
    int row0 = (blockIdx.x >> 2) * 128;

    #pragma unroll
    for (int i = 0; i < 4; i++) {
        int fidx = t + 256 * i;            // 1024 float4
        int k  = fidx >> 3;
        int c4 = fidx & 7;
        *(float4*)(sW + k * 32 + c4 * 4) =
            *(const float4*)(W + (size_t)k * 128 + col0 + c4 * 4);
    }

    // A-stage source address for (stage float4 index f, chunk kb)
    auto a_src = [&](int f, int kb) -> const float* {
        int rowi = f >> 2;                 // 0..127
        int q    = f & 3;                  // float4 within 16 floats
        int rr = row0 + rowi; if (rr > n - 1) rr = n - 1;
        return a_blocked
            ? (A + ((size_t)(kb >> 1) * ns + rr) * 32 + (kb & 1) * 16 + q * 4)
            : (A + (size_t)rr * 128 + kb * 16 + q * 4);
    };

    // stage kb=0 into buffer 0
    {
        float4 v0 = *(const float4*)a_src(t, 0);
        float4 v1 = *(const float4*)a_src(t + 256, 0);
        int f0 = t, f1 = t + 256;
        *(float4*)(&sA[0][(f0 >> 2) * 16 + (f0 & 3) * 4]) = v0;
        *(float4*)(&sA[1 - 1][(f1 >> 2) * 16 + (f1 & 3) * 4]) = v1;
    }
    __syncthreads();

    int cg = (t & 7) * 4;          // 4 cols within the 32-col tile
    int g8 = (t >> 3);             // row group 0..31

    float acc[4][4];
    #pragma unroll
    for (int j = 0; j < 4; j++)
        #pragma unroll
        for (int c = 0; c < 4; c++) acc[j][c] = 0.f;

    #pragma unroll 1
    for (int kb = 0; kb < 8; kb++) {
        // prefetch next A-tile into registers
        float4 pre0, pre1;
        if (kb < 7) {
            pre0 = *(const float4*)a_src(t, kb + 1);
            pre1 = *(const float4*)a_src(t + 256, kb + 1);
        }

        const float* wbase = sW + kb * 16 * 32 + cg;
        const float* abase = sA[kb & 1];
        #pragma unroll
        for (int kkq = 0; kkq < 4; kkq++) {
            float4 aq[4];
            #pragma unroll
            for (int j = 0; j < 4; j++)
                aq[j] = *(const float4*)(abase + (g8 + 32 * j) * 16 + kkq * 4);
            #pragma unroll
            for (int k2 = 0; k2 < 4; k2++) {
                float4 w = *(const float4*)(wbase + (kkq * 4 + k2) * 32);
                #pragma unroll
                for (int j = 0; j < 4; j++) {
                    float av = (k2 == 0) ? aq[j].x : (k2 == 1) ? aq[j].y
                             : (k2 == 2) ? aq[j].z : aq[j].w;
                    acc[j][0] = fmaf(av, w.x, acc[j][0]);
                    acc[j][1] = fmaf(av, w.y, acc[j][1]);
                    acc[j][2] = fmaf(av, w.z, acc[j][2]);
                    acc[j][3] = fmaf(av, w.w, acc[j][3]);
                }
            }
        }

        if (kb < 7) {
            float* nbuf = sA[(kb + 1) & 1];
            int f0 = t, f1 = t + 256;
            *(float4*)(&nbuf[(f0 >> 2) * 16 + (f0 & 3) * 4]) = pre0;
            *(float4*)(&nbuf[(f1 >> 2) * 16 + (f1 & 3) * 4]) = pre1;
        }
        __syncthreads();
    }

    int cb = col0 + cg;
    float* Cb = C + (size_t)(cb >> 5) * ns * 32 + (cb & 31);
    #pragma unroll
    for (int j = 0; j < 4; j++) {
        int rr = row0 + g8 + 32 * j;
        if (rr < n) {
            float dsc = dinv[rr];
            *(float4*)(Cb + (size_t)rr * 32) =
                make_float4(acc[j][0] * dsc, acc[j][1] * dsc,
                            acc[j][2] * dsc, acc[j][3] * dsc);
        }
    }
}

// ---- Aggregation: 4 slices x 32ch, 8 nodes/wave x 8 lanes, 128B rows ------
// h holds pre-scaled rows (h*dinv[row]) blocked [4][ns][32]; row n is zeros.
// out[i] = relu( (sum_edges slice[src] + slice[i]) * dinv[i] + b )
__global__ __launch_bounds__(256) void agg_kernel(const float* __restrict__ h,
                                                  const int* __restrict__ row_ptr,
                                                  const unsigned short* __restrict__ csr,
                                                  const float* __restrict__ dinv,
                                                  const float* __restrict__ bias,
                                                  float* __restrict__ out,
                                                  int n, int ns) {
    int p = blockIdx.x & 3;
    int i = (blockIdx.x >> 2) * 32 + (threadIdx.x >> 3);
    int q = threadIdx.x & 7;
    bool valid = (i < n);
    int iv = valid ? i : 0;

    const float* slice  = h   + (size_t)p * ns * 32;
    float*       oslice = out + (size_t)p * ns * 32;

    int beg = row_ptr[iv];
    int end = valid ? row_ptr[iv + 1] : beg;
    int qoff = q << 2;

    float4 acc = make_float4(0.f, 0.f, 0.f, 0.f);

    int e = beg;
    int s0 = (int)__builtin_nontemporal_load(csr + e);
    int s1 = (int)__builtin_nontemporal_load(csr + e + 1);
    int s2 = (int)__builtin_nontemporal_load(csr + e + 2);
    int s3 = (int)__builtin_nontemporal_load(csr + e + 3);

    while (__any(e < end)) {
        int en = e + 4;
        int t0 = (int)__builtin_nontemporal_load(csr + en);
        int t1 = (int)__builtin_nontemporal_load(csr + en + 1);
        int t2 = (int)__builtin_nontemporal_load(csr + en + 2);
        int t3 = (int)__builtin_nontemporal_load(csr + en + 3);

        int g0 = (e     < end) ? s0 : n;
        int g1 = (e + 1 < end) ? s1 : n;
        int g2 = (e + 2 < end) ? s2 : n;
        int g3 = (e + 3 < end) ? s3 : n;

        float4 v0 = *(const float4*)(slice + ((size_t)g0 << 5) + qoff);
        float4 v1 = *(const float4*)(slice + ((size_t)g1 << 5) + qoff);
        float4 v2 = *(const float4*)(slice + ((size_t)g2 << 5) + qoff);
        float4 v3 = *(const float4*)(slice + ((size_t)g3 << 5) + qoff);

        acc.x += v0.x; acc.y += v0.y; acc.z += v0.z; acc.w += v0.w;
        acc.x += v1.x; acc.y += v1.y; acc.z += v1.z; acc.w += v1.w;
        acc.x += v2.x; acc.y += v2.y; acc.z += v2.z; acc.w += v2.w;
        acc.x += v3.x; acc.y += v3.y; acc.z += v3.z; acc.w += v3.w;

        e = en; s0 = t0; s1 = t1; s2 = t2; s3 = t3;
    }

    if (valid) {
        float di = dinv[i];
        float4 self = *(const float4*)(slice + ((size_t)i << 5) + qoff);
        float4 b4   = *(const float4*)(bias + p * 32 + qoff);
        float4 o;
        o.x = fmaxf(fmaf(acc.x + self.x, di, b4.x), 0.f);
        o.y = fmaxf(fmaf(acc.y + self.y, di, b4.y), 0.f);
        o.z = fmaxf(fmaf(acc.z + self.z, di, b4.z), 0.f);
        o.w = fmaxf(fmaf(acc.w + self.w, di, b4.w), 0.f);
        *(float4*)(oslice + ((size_t)i << 5) + qoff) = o;
    }
}

// ---- pool stage 1: deterministic fp64 partials, one slot per (g,s) --------
__global__ __launch_bounds__(128) void pool_partial_kernel(const float* __restrict__ h,
                                                           const int* __restrict__ batch,
                                                           double* __restrict__ partials,
                                                           int n, int ns, int S) {
    int g = blockIdx.x / S;
    int s = blockIdx.x % S;
    int c = threadIdx.x;
    const float* hb = h + (size_t)(c >> 5) * ns * 32 + (c & 31);

    int lo = 0, hi = n;
    while (lo < hi) { int mid = (lo + hi) >> 1; if (batch[mid] < g) lo = mid + 1; else hi = mid; }
    int start = lo;
    lo = start; hi = n;
    while (lo < hi) { int mid = (lo + hi) >> 1; if (batch[mid] < g + 1) lo = mid + 1; else hi = mid; }
    int end = lo;

    int cnt = end - start;
    int per = (cnt + S - 1) / S;
    int rs = start + s * per;
    int re = rs + per; if (re > end) re = end;

    double a0 = 0.0, a1 = 0.0, a2 = 0.0, a3 = 0.0;
    int r = rs;
    for (; r + 4 <= re; r += 4) {
        a0 += (double)hb[(size_t)(r + 0) * 32];
        a1 += (double)hb[(size_t)(r + 1) * 32];
        a2 += (double)hb[(size_t)(r + 2) * 32];
        a3 += (double)hb[(size_t)(r + 3) * 32];
    }
    for (; r < re; r++) a0 += (double)hb[(size_t)r * 32];
    partials[(size_t)(g * S + s) * 128 + c] = (a0 + a1) + (a2 + a3);
}

// ---- pool stage 2: reduce S partials, mean + FC(128->1), fp64 -------------
__global__ __launch_bounds__(128) void pool_fc_final_kernel(const double* __restrict__ partials,
                                                            const int* __restrict__ batch,
                                                            const float* __restrict__ Wfc,
                                                            const float* __restrict__ bfc,
                                                            float* __restrict__ out,
                                                            int n, int S) {
    int g = blockIdx.x;
    int c = threadIdx.x;

    int lo = 0, hi = n;
    while (lo < hi) { int mid = (lo + hi) >> 1; if (batch[mid] < g) lo = mid + 1; else hi = mid; }
    int start = lo;
    lo = start; hi = n;
    while (lo < hi) { int mid = (lo + hi) >> 1; if (batch[mid] < g + 1) lo = mid + 1; else hi = mid; }
    int cnt = lo - start;

    double sum = 0.0;
    for (int s = 0; s < S; s++) sum += partials[(size_t)(g * S + s) * 128 + c];
    double mean = sum / (double)(cnt > 0 ? cnt : 1);
    double v = mean * (double)Wfc[c];

    __shared__ double red[128];
    red[c] = v;
    __syncthreads();
    for (int off = 64; off > 0; off >>= 1) {
        if (c < off) red[c] += red[c + off];
        __syncthreads();
    }
    if (c == 0) out[g] = (float)(red[0] + (double)bfc[0]);
}

// ---------------------------------------------------------------------------
extern "C" void kernel_launch(void* const* d_in, const int* in_sizes, int n_in,
                              void* d_out, int out_size, void* d_ws, size_t ws_size,
                              hipStream_t stream) {
    const float* x          = (const float*)d_in[0];
    const int*   edge_index = (const int*)d_in[1];
    const int*   batch      = (const int*)d_in[2];
    const float* W1  = (const float*)d_in[3];
    const float* b1  = (const float*)d_in[4];
    const float* W2  = (const float*)d_in[5];
    const float* b2  = (const float*)d_in[6];
    const float* Wfc = (const float*)d_in[7];
    const float* bfc = (const float*)d_in[8];
    float* out = (float*)d_out;

    const int N = in_sizes[2];       // 50000
    const int E = in_sizes[1] / 2;   // 1600000
    const int G = out_size;          // 128 graphs
    const int NS = N + 1;            // slice stride in rows (pad row = zeros)

    const int* e_src = edge_index;
    const int* e_dst = edge_index + E;

    char* p = (char*)d_ws;
    auto alloc = [&](size_t bytes) {
        void* r = (void*)p;
        p += (bytes + 255) & ~(size_t)255;
        return r;
    };
    const int S = 8;
    const int NB = (N + 255) / 256;     // scan blocks
    float*          h0        = (float*)alloc((size_t)NS * 128 * 4);
    float*          h1        = (float*)alloc((size_t)NS * 128 * 4);
    unsigned short* csr       = (unsigned short*)alloc(((size_t)E + 1024) * 2);
    int*            row       = (int*)  alloc((size_t)(N + 1) * 4);
    int*            deg       = (int*)  alloc((size_t)N * 4);
    int*            fill      = (int*)  alloc((size_t)N * 4);
    int*            bsum      = (int*)  alloc((size_t)NB * 4);
    int*            boff      = (int*)  alloc((size_t)NB * 4);
    float*          dinv      = (float*)alloc((size_t)N * 4);
    double*         partials  = (double*)alloc((size_t)G * S * 128 * 8);
    (void)ws_size; (void)n_in;

    hipMemsetAsync(deg,  0, (size_t)N * 4, stream);
    hipMemsetAsync(fill, 0, (size_t)N * 4, stream);

    int tb = 256;
    int e4 = (E + 3) / 4;
    count_deg_kernel<<<(e4 + tb - 1) / tb, tb, 0, stream>>>(e_dst, deg, E);
    dinv_kernel<<<(N + tb - 1) / tb, tb, 0, stream>>>(deg, dinv, h0, h1, N, NS);
    scan_blocksum_kernel<<<NB, 256, 0, stream>>>(deg, bsum, N);
    scan_bsum_kernel<<<1, 1024, 0, stream>>>(bsum, boff, NB);
    scan_final_kernel<<<NB, 256, 0, stream>>>(deg, boff, row, N);
    csr_fill_kernel<<<1024, tb, 0, stream>>>(e_src, e_dst, row, fill, csr, E, N);

    int gemm_blocks = 4 * ((N + 127) / 128);
    int agg_blocks  = 4 * ((N + 31) / 32);

    gemm_kernel<<<gemm_blocks, 256, 0, stream>>>(x, W1, dinv, h1, N, NS, 0);
    agg_kernel<<<agg_blocks, 256, 0, stream>>>(h1, row, csr, dinv, b1, h0, N, NS);

    for (int l = 0; l < 3; l++) {
        gemm_kernel<<<gemm_blocks, 256, 0, stream>>>(h0, W2, dinv, h1, N, NS, 1);
        agg_kernel<<<agg_blocks, 256, 0, stream>>>(h1, row, csr, dinv, b2, h0, N, NS);
    }

    pool_partial_kernel<<<G * S, 128, 0, stream>>>(h0, batch, partials, N, NS, S);
    pool_fc_final_kernel<<<G, 128, 0, stream>>>(partials, batch, Wfc, bfc, out, N, S);
}